// Round 2
// baseline (6252.320 us; speedup 1.0000x reference)
//
#include <hip/hip_runtime.h>
#include <cstdint>
#include <cstddef>

typedef float f4 __attribute__((ext_vector_type(4)));

#define N_NODES 2048
#define BATCH 16
#define LSEQ 12
#define MDIM 112
#define GDIM 448                   // 4*M

__device__ __forceinline__ float sigmoidf_(float x) { return 1.0f / (1.0f + expf(-x)); }

// ---------------------------------------------------------------------------
// K1: build X stripe in node-major layout X[k][bb][l][m], bb local to stripe.
// ---------------------------------------------------------------------------
__global__ void build_x_kernel(const float* __restrict__ hist,
                               const float* __restrict__ node_emb,
                               const float* __restrict__ tid_emb,
                               const float* __restrict__ diw_emb,
                               const float* __restrict__ W_in,
                               const float* __restrict__ b_in,
                               float* __restrict__ X,
                               int b_off, int BS)
{
    int flat = blockIdx.x * 256 + threadIdx.x;
    const int total = N_NODES * BS * LSEQ * MDIM;
    if (flat >= total) return;
    int m = flat % MDIM;
    int r = flat / MDIM;
    int l = r % LSEQ; r /= LSEQ;
    int bb = r % BS;
    int k = r / BS;
    int b = b_off + bb;
    const float* h = hist + ((size_t)((b * LSEQ + l) * N_NODES + k)) * 3;
    float c0 = h[0], c1 = h[1], c2 = h[2];
    float v;
    if (m < 64) {
        v = c0 * W_in[m] + c1 * W_in[64 + m] + c2 * W_in[128 + m] + b_in[m];
    } else if (m < 80) {
        v = node_emb[k * 16 + (m - 64)];
    } else if (m < 96) {
        int ti = (int)(c1 * 288.0f);          // truncating cast, matches reference
        v = tid_emb[ti * 16 + (m - 80)];
    } else {
        int di = (int)(c2 * 7.0f);
        v = diw_emb[di * 16 + (m - 96)];
    }
    X[flat] = v;
}

// ---------------------------------------------------------------------------
// K2: A_dy = softmax(relu(E @ E^T), axis=1).  One block per row.
// ---------------------------------------------------------------------------
__global__ void adaptive_adj_kernel(const float* __restrict__ E, float* __restrict__ Ady)
{
    __shared__ float sbuf[N_NODES];
    __shared__ float red[256];
    const int n = blockIdx.x;
    const int tid = threadIdx.x;
    float en[16];
#pragma unroll
    for (int i = 0; i < 16; ++i) en[i] = E[n * 16 + i];
    float lmax = -3.4e38f;
    for (int k = tid; k < N_NODES; k += 256) {
        const float* ek = E + k * 16;
        float d = 0.f;
#pragma unroll
        for (int i = 0; i < 16; ++i) d += en[i] * ek[i];
        d = fmaxf(d, 0.0f);
        sbuf[k] = d;
        lmax = fmaxf(lmax, d);
    }
    red[tid] = lmax; __syncthreads();
    for (int s = 128; s > 0; s >>= 1) {
        if (tid < s) red[tid] = fmaxf(red[tid], red[tid + s]);
        __syncthreads();
    }
    float mx = red[0];
    __syncthreads();
    float lsum = 0.f;
    for (int k = tid; k < N_NODES; k += 256) {
        float e = expf(sbuf[k] - mx);
        sbuf[k] = e;
        lsum += e;
    }
    red[tid] = lsum; __syncthreads();
    for (int s = 128; s > 0; s >>= 1) {
        if (tid < s) red[tid] += red[tid + s];
        __syncthreads();
    }
    float tot = red[0];
    __syncthreads();
    for (int k = tid; k < N_NODES; k += 256)
        Ady[(size_t)n * N_NODES + k] = sbuf[k] / tot;
}

// ---------------------------------------------------------------------------
// K3: fp32 SGEMM  C[2048][ncols] = A[2048][2048] @ B[2048][ncols]
// 128x128 tile, BK=16, 256 threads, 8x8 microtile as 2x2 blocks of float4.
// ncols must be a multiple of 128.
// ---------------------------------------------------------------------------
__global__ __launch_bounds__(256) void sgemm_kernel(const float* __restrict__ A,
                                                    const float* __restrict__ B,
                                                    float* __restrict__ C,
                                                    int ncols)
{
    __shared__ float As[16][132];   // transposed: As[k][m]
    __shared__ float Bs[16][128];   // direct: Bs[k][j]
    const int tid = threadIdx.x;
    const int tx = tid & 15;        // j dimension
    const int ty = tid >> 4;        // m dimension
    const int m0 = blockIdx.y * 128;
    const int j0 = blockIdx.x * 128;

    const int arow = tid >> 2;          // 0..63
    const int akc  = (tid & 3) << 2;    // 0,4,8,12
    const int brow = tid >> 5;          // 0..7
    const int bjc  = (tid & 31) << 2;   // 0..124

    const size_t ldb = (size_t)ncols;
    const float* Aptr0 = A + (size_t)(m0 + arow) * 2048 + akc;
    const float* Aptr1 = A + (size_t)(m0 + arow + 64) * 2048 + akc;
    const float* Bptr0 = B + (size_t)brow * ldb + j0 + bjc;
    const float* Bptr1 = B + (size_t)(brow + 8) * ldb + j0 + bjc;

    f4 a0 = *(const f4*)Aptr0;
    f4 a1 = *(const f4*)Aptr1;
    f4 b0 = *(const f4*)Bptr0;
    f4 b1 = *(const f4*)Bptr1;

    f4 acc[2][2][4];
#pragma unroll
    for (int p = 0; p < 2; ++p)
#pragma unroll
        for (int q = 0; q < 2; ++q)
#pragma unroll
            for (int i = 0; i < 4; ++i)
#pragma unroll
                for (int e = 0; e < 4; ++e) acc[p][q][i][e] = 0.f;

    for (int kt = 0; kt < 2048; kt += 16) {
        __syncthreads();
#pragma unroll
        for (int i = 0; i < 4; ++i) {
            As[akc + i][arow]      = a0[i];
            As[akc + i][arow + 64] = a1[i];
        }
        *(f4*)&Bs[brow][bjc]     = b0;
        *(f4*)&Bs[brow + 8][bjc] = b1;
        __syncthreads();
        if (kt + 16 < 2048) {   // prefetch next tile into regs
            a0 = *(const f4*)(Aptr0 + kt + 16);
            a1 = *(const f4*)(Aptr1 + kt + 16);
            b0 = *(const f4*)(Bptr0 + (size_t)(kt + 16) * ldb);
            b1 = *(const f4*)(Bptr1 + (size_t)(kt + 16) * ldb);
        }
#pragma unroll
        for (int kk = 0; kk < 16; ++kk) {
            f4 aA = *(const f4*)&As[kk][ty * 4];
            f4 aB = *(const f4*)&As[kk][64 + ty * 4];
            f4 bA = *(const f4*)&Bs[kk][tx * 4];
            f4 bB = *(const f4*)&Bs[kk][64 + tx * 4];
#pragma unroll
            for (int i = 0; i < 4; ++i) {
                acc[0][0][i] += aA[i] * bA;
                acc[0][1][i] += aA[i] * bB;
                acc[1][0][i] += aB[i] * bA;
                acc[1][1][i] += aB[i] * bB;
            }
        }
    }
#pragma unroll
    for (int p = 0; p < 2; ++p)
#pragma unroll
        for (int i = 0; i < 4; ++i) {
            size_t row = (size_t)(m0 + p * 64 + ty * 4 + i);
            *(f4*)&C[row * ldb + j0 + tx * 4]      = acc[p][0][i];
            *(f4*)&C[row * ldb + j0 + 64 + tx * 4] = acc[p][1][i];
        }
}

// ---------------------------------------------------------------------------
// K4: fused gates GEMM (xa @ W + b) + LSTM-style c recurrence over L=12.
// 256 threads = 4 gate-waves x (16 m-threads x 4 n-threads), 32 nodes/block.
// blockIdx.y = local batch within stripe.
// ---------------------------------------------------------------------------
__global__ __launch_bounds__(256) void lstm_kernel(const float* __restrict__ XA,
                                                   const float* __restrict__ W,
                                                   const float* __restrict__ bias,
                                                   float* __restrict__ Hout,
                                                   int b_off, int BS)
{
    __shared__ float xa_s[32][113];
    __shared__ float c_s[32][113];
    __shared__ float t1_s[32][113];
    const int tid  = threadIdx.x;
    const int co   = tid >> 6;      // 0:i 1:f 2:g 3:o
    const int lane = tid & 63;
    const int mt   = lane & 15;     // owns m = mt + 16*mm, mm=0..6
    const int nt   = lane >> 4;     // owns nodes nt*8 .. nt*8+7
    const int n0   = blockIdx.x * 32;
    const int bb   = blockIdx.y;    // local batch
    const int b    = b_off + bb;    // global batch

    for (int e = tid; e < 32 * 113; e += 256) (&c_s[0][0])[e] = 0.f;

    const float* Wc = W + co * 112;
    float bia[7];
#pragma unroll
    for (int mm = 0; mm < 7; ++mm) bia[mm] = bias[co * 112 + mt + mm * 16];

    float acc[8][7];

    for (int t = 0; t < LSEQ; ++t) {
        __syncthreads();
        for (int e = tid; e < 32 * 112; e += 256) {
            int n = e / 112;
            int k = e - n * 112;
            xa_s[n][k] = XA[(((size_t)(n0 + n) * BS + bb) * LSEQ + t) * MDIM + k];
        }
        __syncthreads();
#pragma unroll
        for (int nn = 0; nn < 8; ++nn)
#pragma unroll
            for (int mm = 0; mm < 7; ++mm) acc[nn][mm] = bia[mm];
#pragma unroll 4
        for (int k = 0; k < 112; ++k) {
            float w[7];
#pragma unroll
            for (int mm = 0; mm < 7; ++mm) w[mm] = Wc[k * GDIM + mt + mm * 16];
#pragma unroll
            for (int nn = 0; nn < 8; ++nn) {
                float a = xa_s[nt * 8 + nn][k];
#pragma unroll
                for (int mm = 0; mm < 7; ++mm) acc[nn][mm] = fmaf(a, w[mm], acc[nn][mm]);
            }
        }
        if (co == 0) {        // i: stash sigmoid(i)
#pragma unroll
            for (int nn = 0; nn < 8; ++nn)
#pragma unroll
                for (int mm = 0; mm < 7; ++mm)
                    t1_s[nt * 8 + nn][mt + mm * 16] = sigmoidf_(acc[nn][mm]);
        } else if (co == 1) { // f: c *= sigmoid(f)
#pragma unroll
            for (int nn = 0; nn < 8; ++nn)
#pragma unroll
                for (int mm = 0; mm < 7; ++mm)
                    c_s[nt * 8 + nn][mt + mm * 16] *= sigmoidf_(acc[nn][mm]);
        }
        __syncthreads();
        if (co == 2) {        // g: c += tanh(g) * sigmoid(i)
#pragma unroll
            for (int nn = 0; nn < 8; ++nn)
#pragma unroll
                for (int mm = 0; mm < 7; ++mm)
                    c_s[nt * 8 + nn][mt + mm * 16] += tanhf(acc[nn][mm]) * t1_s[nt * 8 + nn][mt + mm * 16];
        }
        if (t == LSEQ - 1) {
            __syncthreads();
            if (co == 3) {    // o: h = sigmoid(o) * tanh(c)
#pragma unroll
                for (int nn = 0; nn < 8; ++nn)
#pragma unroll
                    for (int mm = 0; mm < 7; ++mm)
                        Hout[((size_t)b * N_NODES + n0 + nt * 8 + nn) * MDIM + mt + mm * 16]
                            = sigmoidf_(acc[nn][mm]) * tanhf(c_s[nt * 8 + nn][mt + mm * 16]);
            }
        }
    }
}

// ---------------------------------------------------------------------------
// K5: fused decoder. layers 1 and 2 are identical, so
// x[b,o,n] = sum_m h0*Wdec[o,0,m] + h1*(Wdec[o,1,m]+Wdec[o,2,m]) + bdec;
// out[b,p,n] = sum_o Wout[p,o]*x[o] + bout[p].
// ---------------------------------------------------------------------------
__global__ void decode_kernel(const float* __restrict__ H,
                              const float* __restrict__ Wdec,
                              const float* __restrict__ bdec,
                              const float* __restrict__ Wout,
                              const float* __restrict__ bout,
                              float* __restrict__ out)
{
    int g = blockIdx.x * 256 + threadIdx.x;   // g = b*2048 + n
    if (g >= BATCH * N_NODES) return;
    int b = g >> 11;
    int n = g & 2047;
    const float* h0 = H + (size_t)g * MDIM;
    const float* h1 = H + (size_t)BATCH * N_NODES * MDIM + (size_t)g * MDIM;
    float x[12];
#pragma unroll
    for (int o = 0; o < 12; ++o) x[o] = bdec[o];
    for (int m = 0; m < MDIM; ++m) {
        float a0 = h0[m], a1 = h1[m];
#pragma unroll
        for (int o = 0; o < 12; ++o)
            x[o] += a0 * Wdec[(o * 3 + 0) * MDIM + m]
                  + a1 * (Wdec[(o * 3 + 1) * MDIM + m] + Wdec[(o * 3 + 2) * MDIM + m]);
    }
#pragma unroll
    for (int p = 0; p < 12; ++p) {
        float s = bout[p];
#pragma unroll
        for (int o = 0; o < 12; ++o) s += Wout[p * 12 + o] * x[o];
        out[((size_t)b * 12 + p) * N_NODES + n] = s;
    }
}

// ---------------------------------------------------------------------------
extern "C" void kernel_launch(void* const* d_in, const int* in_sizes, int n_in,
                              void* d_out, int out_size, void* d_ws, size_t ws_size,
                              hipStream_t stream)
{
    const float* hist   = (const float*)d_in[0];
    const float* adj    = (const float*)d_in[1];
    const float* node_e = (const float*)d_in[2];
    const float* tid_e  = (const float*)d_in[3];
    const float* diw_e  = (const float*)d_in[4];
    const float* W_in   = (const float*)d_in[5];
    const float* b_in   = (const float*)d_in[6];
    const float* W_pre  = (const float*)d_in[7];
    const float* b_pre  = (const float*)d_in[8];
    const float* E_dy   = (const float*)d_in[9];
    const float* W_dy   = (const float*)d_in[10];
    const float* b_dy   = (const float*)d_in[11];
    const float* W_dec  = (const float*)d_in[12];
    const float* b_dec  = (const float*)d_in[13];
    const float* W_out  = (const float*)d_in[14];
    const float* b_out  = (const float*)d_in[15];
    float* out = (float*)d_out;

    float* ws = (float*)d_ws;
    const size_t ADY_F = (size_t)N_NODES * N_NODES;          // 4,194,304 floats
    const size_t H_F   = (size_t)2 * BATCH * N_NODES * MDIM; // 7,340,032 floats
    const size_t avail = ws_size / sizeof(float);

    // choose largest stripe (batches per stripe) whose X/XA buffers fit d_ws
    int BS = 16;
    while (BS > 2 &&
           ADY_F + H_F + 2 * (size_t)N_NODES * BS * LSEQ * MDIM > avail)
        BS >>= 1;

    const size_t XS_F = (size_t)N_NODES * BS * LSEQ * MDIM;
    float* Ady = ws;
    float* H   = Ady + ADY_F;       // [2][B][N][M]
    float* Xs  = H + H_F;
    float* XAs = Xs + XS_F;
    const int ncols = BS * LSEQ * MDIM;   // multiple of 128 for BS in {2,4,8,16}

    adaptive_adj_kernel<<<N_NODES, 256, 0, stream>>>(E_dy, Ady);

    for (int s = 0; s < BATCH / BS; ++s) {
        const int b_off = s * BS;
        build_x_kernel<<<(N_NODES * BS * LSEQ * MDIM + 255) / 256, 256, 0, stream>>>(
            hist, node_e, tid_e, diw_e, W_in, b_in, Xs, b_off, BS);

        // layer 0: predefined graph
        sgemm_kernel<<<dim3(ncols / 128, N_NODES / 128), 256, 0, stream>>>(adj, Xs, XAs, ncols);
        lstm_kernel<<<dim3(N_NODES / 32, BS), 256, 0, stream>>>(XAs, W_pre, b_pre, H, b_off, BS);

        // layers 1&2 identical: compute once
        sgemm_kernel<<<dim3(ncols / 128, N_NODES / 128), 256, 0, stream>>>(Ady, Xs, XAs, ncols);
        lstm_kernel<<<dim3(N_NODES / 32, BS), 256, 0, stream>>>(
            XAs, W_dy, b_dy, H + (size_t)BATCH * N_NODES * MDIM, b_off, BS);
    }

    decode_kernel<<<(BATCH * N_NODES + 255) / 256, 256, 0, stream>>>(
        H, W_dec, b_dec, W_out, b_out, out);
}

// Round 3
// 2456.015 us; speedup vs baseline: 2.5457x; 2.5457x over previous
//
#include <hip/hip_runtime.h>
#include <cstdint>
#include <cstddef>

typedef float f4 __attribute__((ext_vector_type(4)));

#define N_NODES 2048
#define BATCH 16
#define LSEQ 12
#define MDIM 112
#define GDIM 448                   // 4*M
#define KC 35                      // reduced contraction: 3 hist + 16 tid + 16 diw
#define NCOLS_C 6784               // KC*BATCH*LSEQ = 6720 padded to 53*128

__device__ __forceinline__ float sigmoidf_(float x) { return 1.0f / (1.0f + expf(-x)); }

// ---------------------------------------------------------------------------
// K1: build compact Xc[k][j], j=(b*12+l)*35+c. c:0..2 hist ch, 3..18 tid emb,
// 19..34 diw emb. Pad cols 6720..6783 zeroed.
// ---------------------------------------------------------------------------
__global__ void build_xc_kernel(const float* __restrict__ hist,
                                const float* __restrict__ tid_emb,
                                const float* __restrict__ diw_emb,
                                float* __restrict__ Xc)
{
    int flat = blockIdx.x * 256 + threadIdx.x;
    const int total = N_NODES * NCOLS_C;
    if (flat >= total) return;
    int j = flat % NCOLS_C;
    int k = flat / NCOLS_C;
    if (j >= KC * BATCH * LSEQ) { Xc[flat] = 0.f; return; }
    int c  = j % KC;
    int bl = j / KC;                         // b*12+l
    const float* h = hist + ((size_t)bl * N_NODES + k) * 3;
    float v;
    if (c < 3) {
        v = h[c];
    } else if (c < 19) {
        int ti = (int)(h[1] * 288.0f);       // truncating cast, matches reference
        v = tid_emb[ti * 16 + (c - 3)];
    } else {
        int di = (int)(h[2] * 7.0f);
        v = diw_emb[di * 16 + (c - 19)];
    }
    Xc[flat] = v;
}

// ---------------------------------------------------------------------------
// K2: A_dy = softmax(relu(E @ E^T), axis=1).  One block per row.
// ---------------------------------------------------------------------------
__global__ void adaptive_adj_kernel(const float* __restrict__ E, float* __restrict__ Ady)
{
    __shared__ float sbuf[N_NODES];
    __shared__ float red[256];
    const int n = blockIdx.x;
    const int tid = threadIdx.x;
    float en[16];
#pragma unroll
    for (int i = 0; i < 16; ++i) en[i] = E[n * 16 + i];
    float lmax = -3.4e38f;
    for (int k = tid; k < N_NODES; k += 256) {
        const float* ek = E + k * 16;
        float d = 0.f;
#pragma unroll
        for (int i = 0; i < 16; ++i) d += en[i] * ek[i];
        d = fmaxf(d, 0.0f);
        sbuf[k] = d;
        lmax = fmaxf(lmax, d);
    }
    red[tid] = lmax; __syncthreads();
    for (int s = 128; s > 0; s >>= 1) {
        if (tid < s) red[tid] = fmaxf(red[tid], red[tid + s]);
        __syncthreads();
    }
    float mx = red[0];
    __syncthreads();
    float lsum = 0.f;
    for (int k = tid; k < N_NODES; k += 256) {
        float e = expf(sbuf[k] - mx);
        sbuf[k] = e;
        lsum += e;
    }
    red[tid] = lsum; __syncthreads();
    for (int s = 128; s > 0; s >>= 1) {
        if (tid < s) red[tid] += red[tid + s];
        __syncthreads();
    }
    float tot = red[0];
    __syncthreads();
    for (int k = tid; k < N_NODES; k += 256)
        Ady[(size_t)n * N_NODES + k] = sbuf[k] / tot;
}

// ---------------------------------------------------------------------------
// K3: per-row  node_a[n,0:16] = sum_k A[n,k]*node_emb[k,:],  rs[n] = sum_k A[n,k]
// ---------------------------------------------------------------------------
__global__ void node_rs_kernel(const float* __restrict__ A,
                               const float* __restrict__ node_emb,
                               float* __restrict__ node_a, float* __restrict__ rs)
{
    __shared__ float red[256];
    const int n = blockIdx.x;
    const int tid = threadIdx.x;
    float p[17];
#pragma unroll
    for (int i = 0; i < 17; ++i) p[i] = 0.f;
    for (int k = tid; k < N_NODES; k += 256) {
        float a = A[(size_t)n * N_NODES + k];
        const float* e = node_emb + k * 16;
        p[16] += a;
#pragma unroll
        for (int i = 0; i < 16; ++i) p[i] += a * e[i];
    }
    for (int e = 0; e < 17; ++e) {
        red[tid] = p[e]; __syncthreads();
        for (int s = 128; s > 0; s >>= 1) {
            if (tid < s) red[tid] += red[tid + s];
            __syncthreads();
        }
        if (tid == 0) {
            if (e < 16) node_a[n * 16 + e] = red[0];
            else rs[n] = red[0];
        }
        __syncthreads();
    }
}

// ---------------------------------------------------------------------------
// K4: pack effective weights per layer:
//   Wt[c][g]   = sum_{m<64} W_in[c,m]*W[m,g]          (c = 0..2)
//   Wt[3+e][g] = W[80+e, g]                           (e = 0..31, tid||diw rows)
//   bW1[g]     = sum_{m<64} b_in[m]*W[m,g]
// ---------------------------------------------------------------------------
__global__ void prep_wt_kernel(const float* __restrict__ W_in,
                               const float* __restrict__ b_in,
                               const float* __restrict__ W,
                               float* __restrict__ Wt, float* __restrict__ bW1)
{
    int g = blockIdx.x * 256 + threadIdx.x;
    if (g >= GDIM) return;
#pragma unroll
    for (int c = 0; c < 3; ++c) {
        float s = 0.f;
        for (int m = 0; m < 64; ++m) s += W_in[c * 64 + m] * W[(size_t)m * GDIM + g];
        Wt[c * GDIM + g] = s;
    }
    float sb = 0.f;
    for (int m = 0; m < 64; ++m) sb += b_in[m] * W[(size_t)m * GDIM + g];
    bW1[g] = sb;
    for (int e = 0; e < 32; ++e)
        Wt[(3 + e) * GDIM + g] = W[(size_t)(80 + e) * GDIM + g];
}

// ---------------------------------------------------------------------------
// K5: gate constants  Gc[n,g] = sum_e node_a[n,e]*W[64+e,g] + rs[n]*bW1[g] + bg[g]
// ---------------------------------------------------------------------------
__global__ void gc_kernel(const float* __restrict__ node_a, const float* __restrict__ rs,
                          const float* __restrict__ W, const float* __restrict__ bW1,
                          const float* __restrict__ bg, float* __restrict__ Gc)
{
    int idx = blockIdx.x * 256 + threadIdx.x;
    if (idx >= N_NODES * GDIM) return;
    int g = idx % GDIM;
    int n = idx / GDIM;
    float s = bg[g] + rs[n] * bW1[g];
    const float* na = node_a + n * 16;
#pragma unroll
    for (int e = 0; e < 16; ++e) s += na[e] * W[(size_t)(64 + e) * GDIM + g];
    Gc[idx] = s;
}

// ---------------------------------------------------------------------------
// K6: fp32 SGEMM  C[2048][ncols] = A[2048][2048] @ B[2048][ncols]
// 128x128 tile, BK=16, 256 threads, 8x8 microtile (proven in round 2).
// ---------------------------------------------------------------------------
__global__ __launch_bounds__(256) void sgemm_kernel(const float* __restrict__ A,
                                                    const float* __restrict__ B,
                                                    float* __restrict__ C,
                                                    int ncols)
{
    __shared__ float As[16][132];   // transposed: As[k][m]
    __shared__ float Bs[16][128];   // direct: Bs[k][j]
    const int tid = threadIdx.x;
    const int tx = tid & 15;
    const int ty = tid >> 4;
    const int m0 = blockIdx.y * 128;
    const int j0 = blockIdx.x * 128;

    const int arow = tid >> 2;
    const int akc  = (tid & 3) << 2;
    const int brow = tid >> 5;
    const int bjc  = (tid & 31) << 2;

    const size_t ldb = (size_t)ncols;
    const float* Aptr0 = A + (size_t)(m0 + arow) * 2048 + akc;
    const float* Aptr1 = A + (size_t)(m0 + arow + 64) * 2048 + akc;
    const float* Bptr0 = B + (size_t)brow * ldb + j0 + bjc;
    const float* Bptr1 = B + (size_t)(brow + 8) * ldb + j0 + bjc;

    f4 a0 = *(const f4*)Aptr0;
    f4 a1 = *(const f4*)Aptr1;
    f4 b0 = *(const f4*)Bptr0;
    f4 b1 = *(const f4*)Bptr1;

    f4 acc[2][2][4];
#pragma unroll
    for (int p = 0; p < 2; ++p)
#pragma unroll
        for (int q = 0; q < 2; ++q)
#pragma unroll
            for (int i = 0; i < 4; ++i)
#pragma unroll
                for (int e = 0; e < 4; ++e) acc[p][q][i][e] = 0.f;

    for (int kt = 0; kt < 2048; kt += 16) {
        __syncthreads();
#pragma unroll
        for (int i = 0; i < 4; ++i) {
            As[akc + i][arow]      = a0[i];
            As[akc + i][arow + 64] = a1[i];
        }
        *(f4*)&Bs[brow][bjc]     = b0;
        *(f4*)&Bs[brow + 8][bjc] = b1;
        __syncthreads();
        if (kt + 16 < 2048) {
            a0 = *(const f4*)(Aptr0 + kt + 16);
            a1 = *(const f4*)(Aptr1 + kt + 16);
            b0 = *(const f4*)(Bptr0 + (size_t)(kt + 16) * ldb);
            b1 = *(const f4*)(Bptr1 + (size_t)(kt + 16) * ldb);
        }
#pragma unroll
        for (int kk = 0; kk < 16; ++kk) {
            f4 aA = *(const f4*)&As[kk][ty * 4];
            f4 aB = *(const f4*)&As[kk][64 + ty * 4];
            f4 bA = *(const f4*)&Bs[kk][tx * 4];
            f4 bB = *(const f4*)&Bs[kk][64 + tx * 4];
#pragma unroll
            for (int i = 0; i < 4; ++i) {
                acc[0][0][i] += aA[i] * bA;
                acc[0][1][i] += aA[i] * bB;
                acc[1][0][i] += aB[i] * bA;
                acc[1][1][i] += aB[i] * bB;
            }
        }
    }
#pragma unroll
    for (int p = 0; p < 2; ++p)
#pragma unroll
        for (int i = 0; i < 4; ++i) {
            size_t row = (size_t)(m0 + p * 64 + ty * 4 + i);
            *(f4*)&C[row * ldb + j0 + tx * 4]      = acc[p][0][i];
            *(f4*)&C[row * ldb + j0 + 64 + tx * 4] = acc[p][1][i];
        }
}

// ---------------------------------------------------------------------------
// K7: fused gates (35-term contraction) + LSTM c-recurrence over L=12.
// gates[n,b,t,g] = Gc[n,g] + sum_{c<35} XA[n,(b*12+t)*35+c] * Wt[c,g]
// 256 thr = 4 gate-waves x (16 mt x 4 nt), 32 nodes/block, blockIdx.y = batch.
// ---------------------------------------------------------------------------
__global__ __launch_bounds__(256) void lstm2_kernel(const float* __restrict__ XA,
                                                    const float* __restrict__ Wt,
                                                    const float* __restrict__ Gc,
                                                    float* __restrict__ Hout)
{
    __shared__ float xa_s[32][37];
    __shared__ float c_s[32][113];
    __shared__ float t1_s[32][113];
    const int tid  = threadIdx.x;
    const int co   = tid >> 6;      // 0:i 1:f 2:g 3:o
    const int lane = tid & 63;
    const int mt   = lane & 15;
    const int nt   = lane >> 4;
    const int n0   = blockIdx.x * 32;
    const int b    = blockIdx.y;

    for (int e = tid; e < 32 * 113; e += 256) (&c_s[0][0])[e] = 0.f;

    const float* Wc  = Wt + co * 112;
    const float* GcB = Gc + co * 112;

    float acc[8][7];

    for (int t = 0; t < LSEQ; ++t) {
        __syncthreads();
        for (int e = tid; e < 32 * KC; e += 256) {
            int n = e / KC;
            int c = e - n * KC;
            xa_s[n][c] = XA[(size_t)(n0 + n) * NCOLS_C + (b * LSEQ + t) * KC + c];
        }
        __syncthreads();
#pragma unroll
        for (int nn = 0; nn < 8; ++nn)
#pragma unroll
            for (int mm = 0; mm < 7; ++mm)
                acc[nn][mm] = GcB[(size_t)(n0 + nt * 8 + nn) * GDIM + mt + mm * 16];
#pragma unroll 5
        for (int k = 0; k < KC; ++k) {
            float w[7];
#pragma unroll
            for (int mm = 0; mm < 7; ++mm) w[mm] = Wc[k * GDIM + mt + mm * 16];
#pragma unroll
            for (int nn = 0; nn < 8; ++nn) {
                float a = xa_s[nt * 8 + nn][k];
#pragma unroll
                for (int mm = 0; mm < 7; ++mm) acc[nn][mm] = fmaf(a, w[mm], acc[nn][mm]);
            }
        }
        if (co == 0) {        // i: stash sigmoid(i)
#pragma unroll
            for (int nn = 0; nn < 8; ++nn)
#pragma unroll
                for (int mm = 0; mm < 7; ++mm)
                    t1_s[nt * 8 + nn][mt + mm * 16] = sigmoidf_(acc[nn][mm]);
        } else if (co == 1) { // f: c *= sigmoid(f)
#pragma unroll
            for (int nn = 0; nn < 8; ++nn)
#pragma unroll
                for (int mm = 0; mm < 7; ++mm)
                    c_s[nt * 8 + nn][mt + mm * 16] *= sigmoidf_(acc[nn][mm]);
        }
        __syncthreads();
        if (co == 2) {        // g: c += tanh(g) * sigmoid(i)
#pragma unroll
            for (int nn = 0; nn < 8; ++nn)
#pragma unroll
                for (int mm = 0; mm < 7; ++mm)
                    c_s[nt * 8 + nn][mt + mm * 16] += tanhf(acc[nn][mm]) * t1_s[nt * 8 + nn][mt + mm * 16];
        }
        if (t == LSEQ - 1) {
            __syncthreads();
            if (co == 3) {    // o: h = sigmoid(o) * tanh(c)
#pragma unroll
                for (int nn = 0; nn < 8; ++nn)
#pragma unroll
                    for (int mm = 0; mm < 7; ++mm)
                        Hout[((size_t)b * N_NODES + n0 + nt * 8 + nn) * MDIM + mt + mm * 16]
                            = sigmoidf_(acc[nn][mm]) * tanhf(c_s[nt * 8 + nn][mt + mm * 16]);
            }
        }
    }
}

// ---------------------------------------------------------------------------
// K8: fused decoder (layers 1 and 2 identical -> weight folding).
// ---------------------------------------------------------------------------
__global__ void decode_kernel(const float* __restrict__ H,
                              const float* __restrict__ Wdec,
                              const float* __restrict__ bdec,
                              const float* __restrict__ Wout,
                              const float* __restrict__ bout,
                              float* __restrict__ out)
{
    int g = blockIdx.x * 256 + threadIdx.x;   // g = b*2048 + n
    if (g >= BATCH * N_NODES) return;
    int b = g >> 11;
    int n = g & 2047;
    const float* h0 = H + (size_t)g * MDIM;
    const float* h1 = H + (size_t)BATCH * N_NODES * MDIM + (size_t)g * MDIM;
    float x[12];
#pragma unroll
    for (int o = 0; o < 12; ++o) x[o] = bdec[o];
    for (int m = 0; m < MDIM; ++m) {
        float a0 = h0[m], a1 = h1[m];
#pragma unroll
        for (int o = 0; o < 12; ++o)
            x[o] += a0 * Wdec[(o * 3 + 0) * MDIM + m]
                  + a1 * (Wdec[(o * 3 + 1) * MDIM + m] + Wdec[(o * 3 + 2) * MDIM + m]);
    }
#pragma unroll
    for (int p = 0; p < 12; ++p) {
        float s = bout[p];
#pragma unroll
        for (int o = 0; o < 12; ++o) s += Wout[p * 12 + o] * x[o];
        out[((size_t)b * 12 + p) * N_NODES + n] = s;
    }
}

// ---------------------------------------------------------------------------
extern "C" void kernel_launch(void* const* d_in, const int* in_sizes, int n_in,
                              void* d_out, int out_size, void* d_ws, size_t ws_size,
                              hipStream_t stream)
{
    const float* hist   = (const float*)d_in[0];
    const float* adj    = (const float*)d_in[1];
    const float* node_e = (const float*)d_in[2];
    const float* tid_e  = (const float*)d_in[3];
    const float* diw_e  = (const float*)d_in[4];
    const float* W_in   = (const float*)d_in[5];
    const float* b_in   = (const float*)d_in[6];
    const float* W_pre  = (const float*)d_in[7];
    const float* b_pre  = (const float*)d_in[8];
    const float* E_dy   = (const float*)d_in[9];
    const float* W_dy   = (const float*)d_in[10];
    const float* b_dy   = (const float*)d_in[11];
    const float* W_dec  = (const float*)d_in[12];
    const float* b_dec  = (const float*)d_in[13];
    const float* W_out  = (const float*)d_in[14];
    const float* b_out  = (const float*)d_in[15];
    float* out = (float*)d_out;

    float* ws = (float*)d_ws;
    const size_t ADY_F = (size_t)N_NODES * N_NODES;           // 4.19M
    const size_t H_F   = (size_t)2 * BATCH * N_NODES * MDIM;  // 7.34M
    const size_t XC_F  = (size_t)N_NODES * NCOLS_C;           // 13.9M

    float* Ady    = ws;                     ws += ADY_F;
    float* H      = ws;                     ws += H_F;
    float* Xc     = ws;                     ws += XC_F;
    float* XA     = ws;                     ws += XC_F;
    float* na_pre = ws;                     ws += (size_t)N_NODES * 16;
    float* na_dy  = ws;                     ws += (size_t)N_NODES * 16;
    float* rs_pre = ws;                     ws += N_NODES;
    float* rs_dy  = ws;                     ws += N_NODES;
    float* Wt_pre = ws;                     ws += (size_t)KC * GDIM;
    float* Wt_dy  = ws;                     ws += (size_t)KC * GDIM;
    float* bW_pre = ws;                     ws += GDIM;
    float* bW_dy  = ws;                     ws += GDIM;
    float* Gc_pre = ws;                     ws += (size_t)N_NODES * GDIM;
    float* Gc_dy  = ws;                     ws += (size_t)N_NODES * GDIM;

    build_xc_kernel<<<(int)((XC_F + 255) / 256), 256, 0, stream>>>(hist, tid_e, diw_e, Xc);
    adaptive_adj_kernel<<<N_NODES, 256, 0, stream>>>(E_dy, Ady);

    node_rs_kernel<<<N_NODES, 256, 0, stream>>>(adj, node_e, na_pre, rs_pre);
    node_rs_kernel<<<N_NODES, 256, 0, stream>>>(Ady, node_e, na_dy, rs_dy);

    prep_wt_kernel<<<2, 256, 0, stream>>>(W_in, b_in, W_pre, Wt_pre, bW_pre);
    prep_wt_kernel<<<2, 256, 0, stream>>>(W_in, b_in, W_dy, Wt_dy, bW_dy);

    gc_kernel<<<(N_NODES * GDIM + 255) / 256, 256, 0, stream>>>(na_pre, rs_pre, W_pre, bW_pre, b_pre, Gc_pre);
    gc_kernel<<<(N_NODES * GDIM + 255) / 256, 256, 0, stream>>>(na_dy, rs_dy, W_dy, bW_dy, b_dy, Gc_dy);

    // layer 0: predefined graph
    sgemm_kernel<<<dim3(NCOLS_C / 128, N_NODES / 128), 256, 0, stream>>>(adj, Xc, XA, NCOLS_C);
    lstm2_kernel<<<dim3(N_NODES / 32, BATCH), 256, 0, stream>>>(XA, Wt_pre, Gc_pre, H);

    // layers 1&2 identical: compute once (dynamic graph)
    sgemm_kernel<<<dim3(NCOLS_C / 128, N_NODES / 128), 256, 0, stream>>>(Ady, Xc, XA, NCOLS_C);
    lstm2_kernel<<<dim3(N_NODES / 32, BATCH), 256, 0, stream>>>(
        XA, Wt_dy, Gc_dy, H + (size_t)BATCH * N_NODES * MDIM);

    decode_kernel<<<(BATCH * N_NODES + 255) / 256, 256, 0, stream>>>(
        H, W_dec, b_dec, W_out, b_out, out);
}